// Round 7
// baseline (324.910 us; speedup 1.0000x reference)
//
#include <hip/hip_runtime.h>
#include <math.h>

// B=2048, L=64. out = sum(kl) + 5*mean_i(log_qz_i - log_qz_product_i) [BETA-1=5]
// lp2[i,j,l] = lp/ln2 = a2*d^2 + b2, a2 = -0.5/ln2*exp(-lv) < 0
// k3: per-(i,l) sum_j 2^(lp2-BVAL) via Schraudolph fast-exp2 (validated r6,
//   absmax 0.0): S += as_float(cvt_u32(lp2s)), coeffs pre-scaled by 2^23 with
//   magic bias folded in; cvt_u32 saturates negatives -> underflow = +0.0.
// k2: t2_ij = dot(z^2,a2)+dot(z,c1)+qc2_j exact, chunked LSE with true max.
// 3 kernels: per-i-tile last-arriver finishers replace the old kc kernel.

#define NB 2048
#define NL 64
#define NE (NB * NL)
#define BVAL 12.0f
#define EXP_SCALE 8388608.0f     // 2^23
#define EXP_MAGIC 1064866805.0f  // 127*2^23 - 486411

typedef float v2f __attribute__((ext_vector_type(2)));

__device__ __forceinline__ v2f fma2(v2f a, v2f b, v2f c) {
  return __builtin_elementwise_fma(a, b, c);
}
__device__ __forceinline__ float exp2_fast_tail(float p) {
  unsigned u;
  asm("v_cvt_u32_f32 %0, %1" : "=v"(u) : "v"(p));
  return __builtin_bit_cast(float, u);
}
__device__ __forceinline__ float wredsum(float v) {
#pragma unroll
  for (int o = 32; o; o >>= 1) v += __shfl_xor(v, o, 64);
  return v;
}
__device__ __forceinline__ float wredmax(float v) {
#pragma unroll
  for (int o = 32; o; o >>= 1) v = fmaxf(v, __shfl_xor(v, o, 64));
  return v;
}

// A: scaled coeffs for k3, exact transposed arrays + qc2 for k2, kl partials,
// zero the 3 counter arrays.
__global__ __launch_bounds__(256) void ka_pre(const float* __restrict__ kl,
                                              const float* __restrict__ zm,
                                              const float* __restrict__ zlv,
                                              float4* __restrict__ PK2,
                                              float* __restrict__ A2T,
                                              float* __restrict__ MA2T,
                                              float* __restrict__ QC2,
                                              float* __restrict__ KLP,
                                              int* __restrict__ CNT2,
                                              int* __restrict__ CNT3,
                                              int* __restrict__ CNTG) {
  const float INVLN2 = 1.4426950408889634f;
  const float LOG2PI = 1.8378770664093453f;
  int tid = threadIdx.x;
  int e = blockIdx.x * 256 + tid;  // < NE
  int j = e >> 6, l = e & 63;
  float lv = zlv[e], m = zm[e];
  float a2 = -0.5f * INVLN2 * __expf(-lv);
  float b2 = -0.5f * INVLN2 * (lv + LOG2PI);
  float c1 = -2.0f * a2 * m;
  float c0 = fmaf(a2 * m, m, b2);
  PK2[e] = make_float4(a2 * EXP_SCALE, c1 * EXP_SCALE,
                       fmaf(c0 - BVAL, EXP_SCALE, EXP_MAGIC), 0.0f);
  A2T[l * NB + j] = a2;
  MA2T[l * NB + j] = c1;
  float q = wredsum(c0);
  if (l == 0) QC2[j] = q;
  float ks = wredsum(kl[e]);
  __shared__ float sk[4];
  if (l == 0) sk[tid >> 6] = ks;
  __syncthreads();
  if (tid == 0) KLP[blockIdx.x] = sk[0] + sk[1] + sk[2] + sk[3];
  if (blockIdx.x == 0) {
    if (tid < 64) {
      CNT2[tid] = 0;
      CNT3[tid] = 0;
    }
    if (tid == 0) *CNTG = 0;
  }
}

// K2: t2 chunked LSE. grid (8 jc, 64 it): block = 256 j x 32 i. Wave w owns
// i's [i0+8w, i0+8w+8) as 4 v2f; lane+jj covers 4x64 j. z and z^2 staged in
// LDS as v2f. Last arriver of 8 jc merges chunks -> PERI_T[i] (log_qz, log2).
__global__ __launch_bounds__(256) void k2_t(const float* __restrict__ zs,
                                            const float* __restrict__ A2T,
                                            const float* __restrict__ MA2T,
                                            const float* __restrict__ QC2,
                                            float* __restrict__ TPM,
                                            float* __restrict__ TPS,
                                            float* __restrict__ PERI_T,
                                            int* __restrict__ CNT2) {
  int jc = blockIdx.x;       // 0..7
  int it = blockIdx.y;       // 0..63
  int i0 = it * 32;
  int tid = threadIdx.x;
  int w = tid >> 6, lane = tid & 63;

  __shared__ v2f ZS[64][16], ZQ[64][16];  // 16 KB
#pragma unroll
  for (int ss = 0; ss < 4; ++ss) {
    int slot = ss * 256 + tid;  // 0..1023
    int k = slot >> 4, c = slot & 15;
    float z0 = zs[(i0 + 2 * c) * NL + k];
    float z1 = zs[(i0 + 2 * c + 1) * NL + k];
    ZS[k][c] = (v2f){z0, z1};
    ZQ[k][c] = (v2f){z0 * z0, z1 * z1};
  }
  __syncthreads();

  int jbase = jc * 256 + lane;
  v2f acc[16];  // [jj][c]
#pragma unroll
  for (int jj = 0; jj < 4; ++jj) {
    float qv = QC2[jbase + jj * 64];
#pragma unroll
    for (int c = 0; c < 4; ++c) acc[jj * 4 + c] = (v2f){qv, qv};
  }
  for (int k = 0; k < 64; ++k) {
    float av[4], mv[4];
#pragma unroll
    for (int jj = 0; jj < 4; ++jj) {
      av[jj] = A2T[k * NB + jbase + jj * 64];
      mv[jj] = MA2T[k * NB + jbase + jj * 64];
    }
    v2f zp[4], zq[4];
#pragma unroll
    for (int c = 0; c < 4; ++c) {
      zp[c] = ZS[k][(w << 2) | c];
      zq[c] = ZQ[k][(w << 2) | c];
    }
#pragma unroll
    for (int jj = 0; jj < 4; ++jj) {
      v2f a2v = (v2f){av[jj], av[jj]}, m2v = (v2f){mv[jj], mv[jj]};
#pragma unroll
      for (int c = 0; c < 4; ++c) {
        acc[jj * 4 + c] = fma2(zq[c], a2v, acc[jj * 4 + c]);
        acc[jj * 4 + c] = fma2(zp[c], m2v, acc[jj * 4 + c]);
      }
    }
  }
  // per-wave LSE over this chunk's 256 j (4 jj x 64 lanes) for 8 private i's
#pragma unroll
  for (int c = 0; c < 4; ++c) {
    float m0 = fmaxf(fmaxf(acc[c].x, acc[4 + c].x),
                     fmaxf(acc[8 + c].x, acc[12 + c].x));
    float m1 = fmaxf(fmaxf(acc[c].y, acc[4 + c].y),
                     fmaxf(acc[8 + c].y, acc[12 + c].y));
    float M0 = wredmax(m0), M1 = wredmax(m1);
    float s0 = 0.0f, s1 = 0.0f;
#pragma unroll
    for (int jj = 0; jj < 4; ++jj) {
      s0 += __builtin_amdgcn_exp2f(acc[jj * 4 + c].x - M0);
      s1 += __builtin_amdgcn_exp2f(acc[jj * 4 + c].y - M1);
    }
    s0 = wredsum(s0);
    s1 = wredsum(s1);
    if (lane == 0) {
      int i = i0 + w * 8 + 2 * c;
      TPM[i * 8 + jc] = M0;
      TPS[i * 8 + jc] = s0;
      TPM[(i + 1) * 8 + jc] = M1;
      TPS[(i + 1) * 8 + jc] = s1;
    }
  }
  __threadfence();
  __syncthreads();
  __shared__ int lastf;
  if (tid == 0)
    lastf = (__hip_atomic_fetch_add(&CNT2[it], 1, __ATOMIC_ACQ_REL,
                                    __HIP_MEMORY_SCOPE_AGENT) == 7);
  __syncthreads();
  if (lastf && tid < 32) {
    int i = i0 + tid;
    float tm[8], Mt = -1e30f;
#pragma unroll
    for (int s = 0; s < 8; ++s) {
      tm[s] = TPM[i * 8 + s];
      Mt = fmaxf(Mt, tm[s]);
    }
    float St = 0.0f;
#pragma unroll
    for (int s = 0; s < 8; ++s)
      St += TPS[i * 8 + s] * __builtin_amdgcn_exp2f(tm[s] - Mt);
    PERI_T[i] = Mt + __builtin_amdgcn_logf(St);
  }
}

// K3: per-(i,l) sum_j 2^(lp2-BVAL), fast-exp2. grid (16 jc, 64 it of 32 i),
// 1024 blocks (4/CU). Wave w: 32 j's; 32 i/thread as 16 v2f. Block combines
// 4 waves via LDS -> slab SP[jc]. Last arriver of 16 jc per tile computes
// log2+sum_l -> DIF[i] = PERI_T[i] - lqp2_i. 64th finisher does final scalar.
__global__ __launch_bounds__(256) void k3_lse(const float* __restrict__ zs,
                                              const float4* __restrict__ PK2,
                                              float* __restrict__ SP,
                                              const float* __restrict__ PERI_T,
                                              const float* __restrict__ KLP,
                                              float* __restrict__ DIF,
                                              int* __restrict__ CNT3,
                                              int* __restrict__ CNTG,
                                              float* __restrict__ out) {
  int jc = blockIdx.x;       // 0..15
  int it = blockIdx.y;       // 0..63
  int i0 = it * 32;
  int tid = threadIdx.x;
  int w = tid >> 6, l = tid & 63;
  const float4* p = PK2 + (size_t)(jc * 128 + w * 32) * NL + l;
  v2f zr[16];
#pragma unroll
  for (int r = 0; r < 16; ++r) {
    zr[r].x = zs[(i0 + 2 * r) * NL + l];
    zr[r].y = zs[(i0 + 2 * r + 1) * NL + l];
  }
  v2f S[16];
#pragma unroll
  for (int r = 0; r < 16; ++r) S[r] = (v2f){0.0f, 0.0f};
#pragma unroll 2
  for (int jj = 0; jj < 32; ++jj) {
    float4 c = p[(size_t)jj * NL];
    v2f ca = (v2f){c.x, c.x}, cb = (v2f){c.y, c.y}, cc = (v2f){c.z, c.z};
#pragma unroll
    for (int r = 0; r < 16; ++r) {
      v2f t = fma2(zr[r], ca, cb);
      v2f pa = fma2(t, zr[r], cc);
      v2f e;
      e.x = exp2_fast_tail(pa.x);
      e.y = exp2_fast_tail(pa.y);
      S[r] += e;
    }
  }
  __shared__ float lss[4][32][64];  // 32 KB
#pragma unroll
  for (int r = 0; r < 16; ++r) {
    lss[w][2 * r][l] = S[r].x;
    lss[w][2 * r + 1][l] = S[r].y;
  }
  __syncthreads();
  for (int pp = tid; pp < 2048; pp += 256) {
    int ii = pp >> 6, ll = pp & 63;
    float Sc = lss[0][ii][ll] + lss[1][ii][ll] + lss[2][ii][ll] + lss[3][ii][ll];
    SP[(size_t)jc * NE + (size_t)(i0 + ii) * NL + ll] = Sc;
  }
  __threadfence();
  __syncthreads();
  __shared__ int lastf;
  if (tid == 0)
    lastf = (__hip_atomic_fetch_add(&CNT3[it], 1, __ATOMIC_ACQ_REL,
                                    __HIP_MEMORY_SCOPE_AGENT) == 15);
  __syncthreads();
  if (!lastf) return;
  // tile finisher: 32 i's; wave w handles i = i0 + w*8 + r
#pragma unroll
  for (int r = 0; r < 8; ++r) {
    int i = i0 + w * 8 + r;
    float S16 = 0.0f;
#pragma unroll
    for (int s = 0; s < 16; ++s) S16 += SP[(size_t)s * NE + (size_t)i * NL + l];
    float val = __builtin_amdgcn_logf(S16);  // log2
    float lqp2 = wredsum(val) + 64.0f * BVAL;
    if (l == 0) DIF[i] = PERI_T[i] - lqp2;
  }
  __threadfence();
  __syncthreads();
  __shared__ int lastg;
  if (tid == 0)
    lastg = (__hip_atomic_fetch_add(CNTG, 1, __ATOMIC_ACQ_REL,
                                    __HIP_MEMORY_SCOPE_AGENT) == 63);
  __syncthreads();
  if (!lastg) return;
  // final scalar
  float a = 0.0f, b = 0.0f;
  for (int x = tid; x < 512; x += 256) a += KLP[x];
  for (int x = tid; x < 2048; x += 256) b += DIF[x];
  float ra = wredsum(a), rb = wredsum(b);
  __shared__ float sa[4], sb[4];
  if (l == 0) {
    sa[w] = ra;
    sb[w] = rb;
  }
  __syncthreads();
  if (tid == 0) {
    const float LN2 = 0.6931471805599453f;
    float ka = sa[0] + sa[1] + sa[2] + sa[3];
    float kb = sb[0] + sb[1] + sb[2] + sb[3];
    out[0] = ka + 5.0f * LN2 * kb * (1.0f / (float)NB);
  }
}

extern "C" void kernel_launch(void* const* d_in, const int* in_sizes, int n_in,
                              void* d_out, int out_size, void* d_ws, size_t ws_size,
                              hipStream_t stream) {
  const float* kl = (const float*)d_in[0];
  const float* zm = (const float*)d_in[1];
  const float* zlv = (const float*)d_in[2];
  const float* zs = (const float*)d_in[3];
  float* ws = (float*)d_ws;

  float* PK2 = ws;                       // 4*NE (2 MB)
  float* A2T = PK2 + 4 * NE;             // NE
  float* MA2T = A2T + NE;                // NE
  float* QC2 = MA2T + NE;                // NB
  float* SP = QC2 + NB;                  // 16*NE (8 MB)
  float* TPM = SP + 16 * (size_t)NE;     // NB*8
  float* TPS = TPM + NB * 8;             // NB*8
  float* KLP = TPS + NB * 8;             // 512
  float* PERI_T = KLP + 512;             // NB
  float* DIF = PERI_T + NB;              // NB
  int* CNT2 = (int*)(DIF + NB);          // 64
  int* CNT3 = CNT2 + 64;                 // 64
  int* CNTG = CNT3 + 64;                 // 1   (~11.3 MB dirty)

  ka_pre<<<NE / 256, 256, 0, stream>>>(kl, zm, zlv, (float4*)PK2, A2T, MA2T, QC2,
                                       KLP, CNT2, CNT3, CNTG);
  k2_t<<<dim3(8, 64), 256, 0, stream>>>(zs, A2T, MA2T, QC2, TPM, TPS, PERI_T,
                                        CNT2);
  k3_lse<<<dim3(16, 64), 256, 0, stream>>>(zs, (const float4*)PK2, SP, PERI_T,
                                           KLP, DIF, CNT3, CNTG, (float*)d_out);
}

// Round 8
// 151.937 us; speedup vs baseline: 2.1384x; 2.1384x over previous
//
#include <hip/hip_runtime.h>
#include <math.h>

// B=2048, L=64. out = sum(kl) + 5*mean_i(log_qz_i - log_qz_product_i) [BETA-1=5]
// lp2[i,j,l] = lp/ln2 = a2*d^2 + b2, a2 = -0.5/ln2*exp(-lv) < 0
// k3: per-(i,l) sum_j 2^(lp2-BVAL) via Schraudolph fast-exp2 (absmax 0.0 at r6/r7):
//   coeffs pre-scaled by 2^23, magic bias folded; v_cvt_u32_f32 saturates
//   negatives -> underflowed terms contribute exactly +0.0.
// k2: t2_ij = dot(z^2,a2)+dot(z,c1)+qc2_j exact, chunked LSE with true max.
// NO device-scope fences in hot kernels (r7: each block's __threadfence cost a
// serialized L2 flush -> 195 us at 9% VALUBusy). Kernel boundaries = coherence.

#define NB 2048
#define NL 64
#define NE (NB * NL)
#define BVAL 12.0f
#define EXP_SCALE 8388608.0f     // 2^23
#define EXP_MAGIC 1064866805.0f  // 127*2^23 - 486411

typedef float v2f __attribute__((ext_vector_type(2)));

__device__ __forceinline__ v2f fma2(v2f a, v2f b, v2f c) {
  return __builtin_elementwise_fma(a, b, c);
}
__device__ __forceinline__ float exp2_fast_tail(float p) {
  unsigned u;
  asm("v_cvt_u32_f32 %0, %1" : "=v"(u) : "v"(p));
  return __builtin_bit_cast(float, u);
}
__device__ __forceinline__ float wredsum(float v) {
#pragma unroll
  for (int o = 32; o; o >>= 1) v += __shfl_xor(v, o, 64);
  return v;
}
__device__ __forceinline__ float wredmax(float v) {
#pragma unroll
  for (int o = 32; o; o >>= 1) v = fmaxf(v, __shfl_xor(v, o, 64));
  return v;
}

// A: scaled coeffs for k3, exact transposed arrays + qc2 for k2, kl partials.
__global__ __launch_bounds__(256) void ka_pre(const float* __restrict__ kl,
                                              const float* __restrict__ zm,
                                              const float* __restrict__ zlv,
                                              float4* __restrict__ PK2,
                                              float* __restrict__ A2T,
                                              float* __restrict__ MA2T,
                                              float* __restrict__ QC2,
                                              float* __restrict__ KLP,
                                              int* __restrict__ CNT) {
  const float INVLN2 = 1.4426950408889634f;
  const float LOG2PI = 1.8378770664093453f;
  int tid = threadIdx.x;
  int e = blockIdx.x * 256 + tid;  // < NE
  int j = e >> 6, l = e & 63;
  float lv = zlv[e], m = zm[e];
  float a2 = -0.5f * INVLN2 * __expf(-lv);
  float b2 = -0.5f * INVLN2 * (lv + LOG2PI);
  float c1 = -2.0f * a2 * m;
  float c0 = fmaf(a2 * m, m, b2);
  PK2[e] = make_float4(a2 * EXP_SCALE, c1 * EXP_SCALE,
                       fmaf(c0 - BVAL, EXP_SCALE, EXP_MAGIC), 0.0f);
  A2T[l * NB + j] = a2;
  MA2T[l * NB + j] = c1;
  float q = wredsum(c0);
  if (l == 0) QC2[j] = q;
  float ks = wredsum(kl[e]);
  __shared__ float sk[4];
  if (l == 0) sk[tid >> 6] = ks;
  __syncthreads();
  if (tid == 0) KLP[blockIdx.x] = sk[0] + sk[1] + sk[2] + sk[3];
  if (blockIdx.x == 0 && tid == 0) *CNT = 0;
}

// K2: t2 chunked LSE (r7 math, proven correct; finisher/fence removed).
// grid (8 jc, 64 it): block = 256 j x 32 i. Wave w owns i's [i0+8w, i0+8w+8)
// as 4 v2f; lane+jj covers 4x64 j. z and z^2 staged in LDS as v2f.
__global__ __launch_bounds__(256) void k2_t(const float* __restrict__ zs,
                                            const float* __restrict__ A2T,
                                            const float* __restrict__ MA2T,
                                            const float* __restrict__ QC2,
                                            float* __restrict__ TPM,
                                            float* __restrict__ TPS) {
  int jc = blockIdx.x;  // 0..7
  int it = blockIdx.y;  // 0..63
  int i0 = it * 32;
  int tid = threadIdx.x;
  int w = tid >> 6, lane = tid & 63;

  __shared__ v2f ZS[64][16], ZQ[64][16];  // 16 KB
#pragma unroll
  for (int ss = 0; ss < 4; ++ss) {
    int slot = ss * 256 + tid;  // 0..1023
    int k = slot >> 4, c = slot & 15;
    float z0 = zs[(i0 + 2 * c) * NL + k];
    float z1 = zs[(i0 + 2 * c + 1) * NL + k];
    ZS[k][c] = (v2f){z0, z1};
    ZQ[k][c] = (v2f){z0 * z0, z1 * z1};
  }
  __syncthreads();

  int jbase = jc * 256 + lane;
  v2f acc[16];  // [jj][c]
#pragma unroll
  for (int jj = 0; jj < 4; ++jj) {
    float qv = QC2[jbase + jj * 64];
#pragma unroll
    for (int c = 0; c < 4; ++c) acc[jj * 4 + c] = (v2f){qv, qv};
  }
  for (int k = 0; k < 64; ++k) {
    float av[4], mv[4];
#pragma unroll
    for (int jj = 0; jj < 4; ++jj) {
      av[jj] = A2T[k * NB + jbase + jj * 64];
      mv[jj] = MA2T[k * NB + jbase + jj * 64];
    }
    v2f zp[4], zq[4];
#pragma unroll
    for (int c = 0; c < 4; ++c) {
      zp[c] = ZS[k][(w << 2) | c];
      zq[c] = ZQ[k][(w << 2) | c];
    }
#pragma unroll
    for (int jj = 0; jj < 4; ++jj) {
      v2f a2v = (v2f){av[jj], av[jj]}, m2v = (v2f){mv[jj], mv[jj]};
#pragma unroll
      for (int c = 0; c < 4; ++c) {
        acc[jj * 4 + c] = fma2(zq[c], a2v, acc[jj * 4 + c]);
        acc[jj * 4 + c] = fma2(zp[c], m2v, acc[jj * 4 + c]);
      }
    }
  }
  // per-wave LSE over this chunk's 256 j (4 jj x 64 lanes) for 8 private i's
#pragma unroll
  for (int c = 0; c < 4; ++c) {
    float m0 = fmaxf(fmaxf(acc[c].x, acc[4 + c].x),
                     fmaxf(acc[8 + c].x, acc[12 + c].x));
    float m1 = fmaxf(fmaxf(acc[c].y, acc[4 + c].y),
                     fmaxf(acc[8 + c].y, acc[12 + c].y));
    float M0 = wredmax(m0), M1 = wredmax(m1);
    float s0 = 0.0f, s1 = 0.0f;
#pragma unroll
    for (int jj = 0; jj < 4; ++jj) {
      s0 += __builtin_amdgcn_exp2f(acc[jj * 4 + c].x - M0);
      s1 += __builtin_amdgcn_exp2f(acc[jj * 4 + c].y - M1);
    }
    s0 = wredsum(s0);
    s1 = wredsum(s1);
    if (lane == 0) {
      int i = i0 + w * 8 + 2 * c;
      TPM[i * 8 + jc] = M0;
      TPS[i * 8 + jc] = s0;
      TPM[(i + 1) * 8 + jc] = M1;
      TPS[(i + 1) * 8 + jc] = s1;
    }
  }
}

// K3 (r6-benched form): per-(i,l) sum_j 2^(lp2-BVAL), fast-exp2.
// grid (8 jc, 64 i-tiles of 32), 256 thr = 4 waves; wave w: 64 j's.
// 32 i's/thread as 16 v2f. Block-combine 4 waves via LDS -> slab SP[jc]
// (8 slabs, 4 MB, L2-resident). No fences.
__global__ __launch_bounds__(256) void k3_lse(const float* __restrict__ zs,
                                              const float4* __restrict__ PK2,
                                              float* __restrict__ SP) {
  int jc = blockIdx.x;       // 0..7
  int i0 = blockIdx.y * 32;  // i tile base
  int tid = threadIdx.x;
  int w = tid >> 6, l = tid & 63;
  const float4* p = PK2 + (size_t)(jc * 256 + w * 64) * NL + l;
  v2f zr[16];
#pragma unroll
  for (int r = 0; r < 16; ++r) {
    zr[r].x = zs[(i0 + 2 * r) * NL + l];
    zr[r].y = zs[(i0 + 2 * r + 1) * NL + l];
  }
  v2f S[16];
#pragma unroll
  for (int r = 0; r < 16; ++r) S[r] = (v2f){0.0f, 0.0f};
#pragma unroll 2
  for (int jj = 0; jj < 64; ++jj) {
    float4 c = p[(size_t)jj * NL];
    v2f ca = (v2f){c.x, c.x}, cb = (v2f){c.y, c.y}, cc = (v2f){c.z, c.z};
#pragma unroll
    for (int r = 0; r < 16; ++r) {
      v2f t = fma2(zr[r], ca, cb);
      v2f pa = fma2(t, zr[r], cc);
      v2f e;
      e.x = exp2_fast_tail(pa.x);
      e.y = exp2_fast_tail(pa.y);
      S[r] += e;
    }
  }
  __shared__ float lss[4][32][64];  // 32 KB
#pragma unroll
  for (int r = 0; r < 16; ++r) {
    lss[w][2 * r][l] = S[r].x;
    lss[w][2 * r + 1][l] = S[r].y;
  }
  __syncthreads();
  for (int pp = tid; pp < 2048; pp += 256) {
    int ii = pp >> 6, ll = pp & 63;
    float Sc = lss[0][ii][ll] + lss[1][ii][ll] + lss[2][ii][ll] + lss[3][ii][ll];
    SP[(size_t)jc * NE + (size_t)(i0 + ii) * NL + ll] = Sc;
  }
}

// C: per-i finish (sum 8 slabs -> log2 -> sum_l + 64*BVAL; merge 8 t-chunks) +
// last-block global reduce. 512 blocks, wave = one i. (Proven r5/r6 form —
// agent-scope atomics only in this tiny tail kernel.)
__global__ __launch_bounds__(256) void kc_fin(const float* __restrict__ SP,
                                              const float* __restrict__ TPM,
                                              const float* __restrict__ TPS,
                                              const float* __restrict__ KLP,
                                              float* __restrict__ PERB,
                                              int* __restrict__ CNT,
                                              float* __restrict__ out) {
  int tid = threadIdx.x;
  int w = tid >> 6, l = tid & 63;
  int i = blockIdx.x * 4 + w;
  float S = 0.0f;
#pragma unroll
  for (int s = 0; s < 8; ++s) S += SP[(size_t)s * NE + (size_t)i * NL + l];
  float val = __builtin_amdgcn_logf(S);  // log2
  float lqp2 = wredsum(val) + 64.0f * BVAL;
  float tm = (l < 8) ? TPM[i * 8 + l] : -1e30f;
  float ts = (l < 8) ? TPS[i * 8 + l] : 0.0f;
  float Mt = wredmax(tm);
  float St = wredsum(ts * __builtin_amdgcn_exp2f(tm - Mt));
  float lqz2 = Mt + __builtin_amdgcn_logf(St);
  __shared__ float sblk[4];
  if (l == 0) sblk[w] = lqz2 - lqp2;
  __syncthreads();
  __shared__ int slast;
  if (tid == 0) {
    float v = sblk[0] + sblk[1] + sblk[2] + sblk[3];
    __hip_atomic_store(&PERB[blockIdx.x], v, __ATOMIC_RELEASE, __HIP_MEMORY_SCOPE_AGENT);
    int old = __hip_atomic_fetch_add(CNT, 1, __ATOMIC_ACQ_REL, __HIP_MEMORY_SCOPE_AGENT);
    slast = (old == 511) ? 1 : 0;
  }
  __syncthreads();
  if (!slast) return;
  float a = 0.0f, b = 0.0f;
  for (int x = tid; x < 512; x += 256) {
    a += KLP[x];
    b += __hip_atomic_load(&PERB[x], __ATOMIC_ACQUIRE, __HIP_MEMORY_SCOPE_AGENT);
  }
  float ra = wredsum(a), rb = wredsum(b);
  __shared__ float sa[4], sb[4];
  if (l == 0) {
    sa[w] = ra;
    sb[w] = rb;
  }
  __syncthreads();
  if (tid == 0) {
    const float LN2 = 0.6931471805599453f;
    float ka = sa[0] + sa[1] + sa[2] + sa[3];
    float kb = sb[0] + sb[1] + sb[2] + sb[3];
    out[0] = ka + 5.0f * LN2 * kb * (1.0f / (float)NB);
  }
}

extern "C" void kernel_launch(void* const* d_in, const int* in_sizes, int n_in,
                              void* d_out, int out_size, void* d_ws, size_t ws_size,
                              hipStream_t stream) {
  const float* kl = (const float*)d_in[0];
  const float* zm = (const float*)d_in[1];
  const float* zlv = (const float*)d_in[2];
  const float* zs = (const float*)d_in[3];
  float* ws = (float*)d_ws;

  float* PK2 = ws;                  // 4*NE (2 MB)
  float* A2T = PK2 + 4 * NE;        // NE
  float* MA2T = A2T + NE;           // NE
  float* QC2 = MA2T + NE;           // NB
  float* SP = QC2 + NB;             // 8*NE (4 MB)
  float* TPM = SP + 8 * NE;         // NB*8
  float* TPS = TPM + NB * 8;        // NB*8
  float* KLP = TPS + NB * 8;        // 512
  float* PERB = KLP + 512;          // 512
  int* CNT = (int*)(PERB + 512);    // 1   (~7.2 MB dirty)

  ka_pre<<<NE / 256, 256, 0, stream>>>(kl, zm, zlv, (float4*)PK2, A2T, MA2T, QC2,
                                       KLP, CNT);
  k2_t<<<dim3(8, 64), 256, 0, stream>>>(zs, A2T, MA2T, QC2, TPM, TPS);
  k3_lse<<<dim3(8, NB / 32), 256, 0, stream>>>(zs, (const float4*)PK2, SP);
  kc_fin<<<512, 256, 0, stream>>>(SP, TPM, TPS, KLP, PERB, CNT, (float*)d_out);
}